// Round 4
// baseline (573.051 us; speedup 1.0000x reference)
//
#include <hip/hip_runtime.h>
#include <hip/hip_bf16.h>

#define NN 50000
#define EE 500000
#define DIN 64
#define HIDD 128
#define NG 64
#define NB1 49  // ceil(NN/1024) scan blocks

typedef short short8 __attribute__((ext_vector_type(8)));
typedef float f32x4 __attribute__((ext_vector_type(4)));

__device__ __forceinline__ short f2bf(float f) {
  unsigned u = __float_as_uint(f);
  u += 0x7fffu + ((u >> 16) & 1u);  // RNE
  return (short)(u >> 16);
}

struct BiasW { const float* b[4]; };
struct PrepW { const float* w[12]; };

// ---------------- CSR build ----------------
__global__ __launch_bounds__(256) void count_kernel(const int* __restrict__ ei,
                                                    int* __restrict__ cnt, int E) {
  int e = blockIdx.x * 256 + threadIdx.x;
  if (e < E) atomicAdd(&cnt[ei[E + e]], 1);
}

__global__ __launch_bounds__(1024) void scan1_kernel(const int* __restrict__ cnts,
                                                     int* __restrict__ starts,
                                                     int* __restrict__ btot) {
  __shared__ int sh[1024];
  int t = threadIdx.x;
  int idx = blockIdx.x * 1024 + t;
  int v = (idx < NN) ? cnts[idx] : 0;
  sh[t] = v;
  __syncthreads();
  for (int off = 1; off < 1024; off <<= 1) {
    int add = (t >= off) ? sh[t - off] : 0;
    __syncthreads();
    sh[t] += add;
    __syncthreads();
  }
  if (idx < NN) starts[idx] = sh[t] - v;
  if (t == 1023) btot[blockIdx.x] = sh[1023];
}

__global__ __launch_bounds__(64) void scan2_kernel(const int* __restrict__ btot,
                                                   int* __restrict__ boff,
                                                   int* __restrict__ starts) {
  int t = threadIdx.x;
  int orig = (t < NB1) ? btot[t] : 0;
  int v = orig;
  for (int off = 1; off < 64; off <<= 1) {
    int n_ = __shfl_up(v, off);
    if (t >= off) v += n_;
  }
  if (t < NB1) boff[t] = v - orig;
  if (t == NB1 - 1) starts[NN] = v;
}

__global__ __launch_bounds__(256) void scan3_kernel(int* __restrict__ starts,
                                                    const int* __restrict__ boff,
                                                    int* __restrict__ pos) {
  int i = blockIdx.x * 256 + threadIdx.x;
  if (i < NN) {
    int s = starts[i] + boff[i >> 10];
    starts[i] = s;
    pos[i] = s;
  }
}

__global__ __launch_bounds__(256) void scatter_kernel(const int* __restrict__ ei,
                                                      int* __restrict__ pos,
                                                      int* __restrict__ csr_src, int E) {
  int e = blockIdx.x * 256 + threadIdx.x;
  if (e < E) {
    int dst = ei[E + e];
    int p = atomicAdd(&pos[dst], 1);
    csr_src[p] = ei[e];
  }
}

// ---------------- weight prep: transpose + cast to bf16 ----------------
// wT layout: mats 0..3 (l0, K=64): [128][64] at m*8192
//            mats 4..11 (layers, K=128): [128][128] at 32768+(m-4)*16384
__global__ __launch_bounds__(256) void prep_kernel(PrepW pw, short* __restrict__ wT) {
  int o = blockIdx.x * 256 + threadIdx.x;
  if (o >= 163840) return;
  int m, local, K;
  if (o < 32768) { m = o >> 13; local = o & 8191; K = 64; }
  else { int oo = o - 32768; m = 4 + (oo >> 14); local = oo & 16383; K = 128; }
  int n = (K == 64) ? (local >> 6) : (local >> 7);
  int k = local & (K - 1);
  wT[o] = f2bf(pw.w[m][(size_t)k * 128 + n]);
}

// ---------------- bf16 MFMA GEMM, 4 mats, B via LDS pipeline ----------------
// 32 rows/block, 4 waves (2 row-groups x 2 col-halves). grid ceil(N/32).
// mat 0 -> Q (f32), 1 -> K (bf16 kv[:,0:128]), 2 -> V (bf16 kv[:,128:256]), 3 -> S (f32)
template <int K>
__global__ __launch_bounds__(256, 3) void gemm_qkvs(
    const float* __restrict__ h, const short* __restrict__ wT, BiasW bw,
    float* __restrict__ qf, unsigned short* __restrict__ kvb,
    float* __restrict__ sf, int N) {
  __shared__ short aS[32 * K];    // swizzled [row][k]
  __shared__ short bS[128 * K];   // swizzled [col][k]
  constexpr int CHB = K / 16;     // uint4 B-chunks per thread
  constexpr int RB = 2 * K;       // bytes per row/col
  constexpr int SLOTS = K / 8;
  const int n0 = blockIdx.x * 32;
  const int t = threadIdx.x;

  // stage A (32 rows x K) f32 -> bf16, XOR-swizzled
  for (int idx = t; idx < 32 * SLOTS; idx += 256) {
    int row = idx / SLOTS, slot = idx % SLOTS;
    int gr = n0 + row;
    float4 f0 = make_float4(0.f, 0.f, 0.f, 0.f), f1 = f0;
    if (gr < N) {
      const float* hp = &h[(size_t)gr * K + slot * 8];
      f0 = *(const float4*)hp;
      f1 = *(const float4*)(hp + 4);
    }
    short8 pk;
    pk[0] = f2bf(f0.x); pk[1] = f2bf(f0.y); pk[2] = f2bf(f0.z); pk[3] = f2bf(f0.w);
    pk[4] = f2bf(f1.x); pk[5] = f2bf(f1.y); pk[6] = f2bf(f1.z); pk[7] = f2bf(f1.w);
    unsigned byte = row * RB + ((slot * 16) ^ ((row & 7) << 4));
    *(short8*)((char*)aS + byte) = pk;
  }

  // prologue: issue global B-loads for mat 0 (in flight across barrier)
  uint4 breg[CHB];
#pragma unroll
  for (int c = 0; c < CHB; ++c)
    breg[c] = *(const uint4*)(wT + (size_t)(c * 256 + t) * 8);

  __syncthreads();  // A visible

  const int l = t & 63, wv = t >> 6;
  const int lr = l & 15, lk = l >> 4;
  const int arow = (wv >> 1) * 16 + lr;
  short8 afrag[K / 32];
#pragma unroll
  for (int ks = 0; ks < K / 32; ++ks) {
    unsigned ab = arow * RB + ((((ks * 4 + lk) * 16)) ^ ((arow & 7) << 4));
    afrag[ks] = *(const short8*)((const char*)aS + ab);
  }

  const int colbase = (wv & 1) * 64;
#pragma unroll
  for (int mat = 0; mat < 4; ++mat) {
    __syncthreads();  // previous mat's bS reads complete
    // write staged B to swizzled LDS (compiler waits vmcnt on breg)
#pragma unroll
    for (int c = 0; c < CHB; ++c) {
      int cid = c * 256 + t;
      int col = cid / (K / 8), kslot = cid % (K / 8);
      unsigned byte = col * RB + ((kslot * 16) ^ ((col & 7) << 4));
      *(uint4*)((char*)bS + byte) = breg[c];
    }
    // issue next mat's global loads now — hide under MFMA phase
    if (mat < 3) {
      const short* wm = wT + (size_t)(mat + 1) * 128 * K;
#pragma unroll
      for (int c = 0; c < CHB; ++c)
        breg[c] = *(const uint4*)(wm + (size_t)(c * 256 + t) * 8);
    }
    __syncthreads();  // bS visible

    f32x4 acc[4] = {};
#pragma unroll
    for (int ks = 0; ks < K / 32; ++ks) {
#pragma unroll
      for (int cf = 0; cf < 4; ++cf) {
        int col = colbase + cf * 16 + lr;
        unsigned bb = col * RB + (((ks * 64 + lk * 16)) ^ ((col & 7) << 4));
        short8 b = *(const short8*)((const char*)bS + bb);
        acc[cf] = __builtin_amdgcn_mfma_f32_16x16x32_bf16(afrag[ks], b, acc[cf], 0, 0, 0);
      }
    }
    const float* __restrict__ bias = bw.b[mat];
#pragma unroll
    for (int cf = 0; cf < 4; ++cf) {
      int col = colbase + cf * 16 + lr;
      float bv = bias[col];
#pragma unroll
      for (int r = 0; r < 4; ++r) {
        int row = n0 + (wv >> 1) * 16 + lk * 4 + r;
        if (row < N) {
          float val = acc[cf][r] + bv;
          if (mat == 0) qf[(size_t)row * 128 + col] = val;
          else if (mat == 3) sf[(size_t)row * 128 + col] = val;
          else kvb[(size_t)row * 256 + (mat == 2 ? 128 : 0) + col] = (unsigned short)f2bf(val);
        }
      }
    }
  }
}

// ---------------- fused attention + beta gate + LN + GELU ----------------
// one wave per node. lanes 0-31 own K-side (4 channels each), lanes 32-63 own
// V-side/output (4 channels each). ONE uint2 (8B) gather per edge per lane:
// kvu row is 512B = [K 256B | V 256B]; lane reads dwords 2*lane, 2*lane+1.
__global__ __launch_bounds__(256, 4) void attn_fused(
    const float* __restrict__ qf, const unsigned* __restrict__ kvu,
    const float* __restrict__ sf, const int* __restrict__ starts,
    const int* __restrict__ csr, const float* __restrict__ Wbeta,
    const float* __restrict__ lng, const float* __restrict__ lnb,
    float* __restrict__ hout, int N) {
  int wid = (blockIdx.x * 256 + threadIdx.x) >> 6;
  if (wid >= N) return;
  const int lane = threadIdx.x & 63;
  const int cl = lane & 31;  // channel group: channels 4*cl .. 4*cl+3
  const float scale = 0.17677669529663687f;  // 1/sqrt(32)
  float4 q4 = *(const float4*)&qf[(size_t)wid * 128 + 4 * cl];
  q4.x *= scale; q4.y *= scale; q4.z *= scale; q4.w *= scale;
  int s0 = starts[wid], s1 = starts[wid + 1];
  float d = 0.f, ox = 0.f, oy = 0.f, oz = 0.f, ow = 0.f;
  for (int i = s0; i < s1; i += 8) {
    int src[8];
#pragma unroll
    for (int e = 0; e < 8; ++e) {
      int idx = i + e;
      idx = (idx < s1) ? idx : (s1 - 1);
      src[e] = csr[idx];
    }
    uint2 wv2[8];
#pragma unroll
    for (int e = 0; e < 8; ++e)
      wv2[e] = *(const uint2*)&kvu[(size_t)src[e] * 128 + 2 * lane];
#pragma unroll
    for (int e = 0; e < 8; ++e) {
      float fx = __uint_as_float(wv2[e].x << 16);
      float fy = __uint_as_float(wv2[e].x & 0xffff0000u);
      float fz = __uint_as_float(wv2[e].y << 16);
      float fw = __uint_as_float(wv2[e].y & 0xffff0000u);
      // lanes 0-31: partial QK dot over this lane's 4 channels
      float part = q4.x * fx + q4.y * fy + q4.z * fz + q4.w * fw;
      part += __shfl_xor(part, 1);
      part += __shfl_xor(part, 2);
      part += __shfl_xor(part, 4);  // head-sum over 8 lanes
      float p = __expf(part);
      p = (i + e < s1) ? p : 0.f;
      float pm = __shfl(p, cl);  // broadcast head-p to matching V lane
      d += p;                    // meaningful in lanes 0-31
      ox = fmaf(pm, fx, ox); oy = fmaf(pm, fy, oy);  // meaningful in lanes 32-63
      oz = fmaf(pm, fz, oz); ow = fmaf(pm, fw, ow);
    }
  }
  float dv = __shfl(d, cl);
  float inv = dv > 0.f ? 1.f / dv : 0.f;
  ox *= inv; oy *= inv; oz *= inv; ow *= inv;
  float4 sv4 = *(const float4*)&sf[(size_t)wid * 128 + 4 * cl];
  float4 wbo = *(const float4*)&Wbeta[4 * cl];
  float4 wbx = *(const float4*)&Wbeta[128 + 4 * cl];
  float4 wbd = *(const float4*)&Wbeta[256 + 4 * cl];
  float bl = ox * wbo.x + oy * wbo.y + oz * wbo.z + ow * wbo.w
           + sv4.x * wbx.x + sv4.y * wbx.y + sv4.z * wbx.z + sv4.w * wbx.w
           + (ox - sv4.x) * wbd.x + (oy - sv4.y) * wbd.y
           + (oz - sv4.z) * wbd.z + (ow - sv4.w) * wbd.w;
  bl += __shfl_xor(bl, 1);  bl += __shfl_xor(bl, 2);  bl += __shfl_xor(bl, 4);
  bl += __shfl_xor(bl, 8);  bl += __shfl_xor(bl, 16);  // sum over 32-lane half
  float beta = 1.f / (1.f + __expf(-bl));
  float hx = beta * sv4.x + (1.f - beta) * ox;
  float hy = beta * sv4.y + (1.f - beta) * oy;
  float hz = beta * sv4.z + (1.f - beta) * oz;
  float hw = beta * sv4.w + (1.f - beta) * ow;
  float s = hx + hy + hz + hw;
  float sq = hx * hx + hy * hy + hz * hz + hw * hw;
  s += __shfl_xor(s, 1);  sq += __shfl_xor(sq, 1);
  s += __shfl_xor(s, 2);  sq += __shfl_xor(sq, 2);
  s += __shfl_xor(s, 4);  sq += __shfl_xor(sq, 4);
  s += __shfl_xor(s, 8);  sq += __shfl_xor(sq, 8);
  s += __shfl_xor(s, 16); sq += __shfl_xor(sq, 16);
  float mu = s * (1.f / 128.f);
  float var = sq * (1.f / 128.f) - mu * mu;
  float rstd = 1.f / sqrtf(var + 1e-5f);
  float4 g4 = *(const float4*)&lng[4 * cl];
  float4 b4 = *(const float4*)&lnb[4 * cl];
  float y0 = (hx - mu) * rstd * g4.x + b4.x;
  float y1 = (hy - mu) * rstd * g4.y + b4.y;
  float y2 = (hz - mu) * rstd * g4.z + b4.z;
  float y3 = (hw - mu) * rstd * g4.w + b4.w;
  y0 = 0.5f * y0 * (1.f + erff(y0 * 0.70710678118654752f));
  y1 = 0.5f * y1 * (1.f + erff(y1 * 0.70710678118654752f));
  y2 = 0.5f * y2 * (1.f + erff(y2 * 0.70710678118654752f));
  y3 = 0.5f * y3 * (1.f + erff(y3 * 0.70710678118654752f));
  if (lane >= 32) {
    float4 o = make_float4(y0, y1, y2, y3);
    *(float4*)&hout[(size_t)wid * 128 + 4 * cl] = o;
  }
}

// ---------------- mean pool ----------------
__global__ __launch_bounds__(256) void pool_kernel(const float* __restrict__ h,
    const int* __restrict__ batch, float* __restrict__ g,
    float* __restrict__ gcnt, int N) {
  __shared__ float accS[NG * HIDD];
  __shared__ float cntS[NG];
  int t = threadIdx.x;
  for (int i = t; i < NG * HIDD; i += 256) accS[i] = 0.f;
  if (t < NG) cntS[t] = 0.f;
  __syncthreads();
  int lane = t & 63, grp = t >> 6;
  for (int n = blockIdx.x * 4 + grp; n < N; n += gridDim.x * 4) {
    int b = batch[n];
    float2 hv = *(const float2*)&h[(size_t)n * HIDD + (lane << 1)];
    atomicAdd(&accS[b * HIDD + (lane << 1)], hv.x);
    atomicAdd(&accS[b * HIDD + (lane << 1) + 1], hv.y);
    if (lane == 0) atomicAdd(&cntS[b], 1.f);
  }
  __syncthreads();
  for (int i = t; i < NG * HIDD; i += 256)
    if (accS[i] != 0.f) atomicAdd(&g[i], accS[i]);
  if (t < NG && cntS[t] != 0.f) atomicAdd(&gcnt[t], cntS[t]);
}

// ---------------- final MLP (single block) ----------------
__global__ __launch_bounds__(256) void final_kernel(const float* __restrict__ g,
    const float* __restrict__ gcnt, const float* __restrict__ W1,
    const float* __restrict__ b1, const float* __restrict__ W2,
    const float* __restrict__ b2, float* __restrict__ out) {
  __shared__ float gS[NG * HIDD];
  __shared__ float hmS[NG * HIDD];
  int t = threadIdx.x;
  for (int i = t; i < NG * HIDD; i += 256) {
    int gr = i >> 7;
    gS[i] = g[i] / fmaxf(gcnt[gr], 1.f);
  }
  __syncthreads();
  for (int i = t; i < NG * HIDD; i += 256) {
    int gr = i >> 7, col = i & 127;
    float s = b1[col];
    for (int k = 0; k < HIDD; ++k) s = fmaf(gS[gr * HIDD + k], W1[k * HIDD + col], s);
    hmS[i] = 0.5f * s * (1.f + erff(s * 0.70710678118654752f));
  }
  __syncthreads();
  if (t < NG) {
    float s = b2[0];
    for (int k = 0; k < HIDD; ++k) s = fmaf(hmS[t * HIDD + k], W2[k], s);
    out[t] = s;
  }
}

extern "C" void kernel_launch(void* const* d_in, const int* in_sizes, int n_in,
                              void* d_out, int out_size, void* d_ws, size_t ws_size,
                              hipStream_t stream) {
  const float* x        = (const float*)d_in[0];
  const int*   ei       = (const int*)d_in[1];
  const int*   batch    = (const int*)d_in[2];
  const float* l0_Wq    = (const float*)d_in[3];
  const float* l0_bq    = (const float*)d_in[4];
  const float* l0_Wk    = (const float*)d_in[5];
  const float* l0_bk    = (const float*)d_in[6];
  const float* l0_Wv    = (const float*)d_in[7];
  const float* l0_bv    = (const float*)d_in[8];
  const float* l0_Ws    = (const float*)d_in[9];
  const float* l0_bs    = (const float*)d_in[10];
  const float* l0_Wbeta = (const float*)d_in[11];
  const float* l0_lng   = (const float*)d_in[12];
  const float* l0_lnb   = (const float*)d_in[13];
  const float* Wq       = (const float*)d_in[14];
  const float* bq       = (const float*)d_in[15];
  const float* Wk       = (const float*)d_in[16];
  const float* bk       = (const float*)d_in[17];
  const float* Wv       = (const float*)d_in[18];
  const float* bv       = (const float*)d_in[19];
  const float* Ws       = (const float*)d_in[20];
  const float* bs       = (const float*)d_in[21];
  const float* Wbeta    = (const float*)d_in[22];
  const float* lng      = (const float*)d_in[23];
  const float* lnb      = (const float*)d_in[24];
  const float* mlp_W1   = (const float*)d_in[25];
  const float* mlp_b1   = (const float*)d_in[26];
  const float* mlp_W2   = (const float*)d_in[27];
  const float* mlp_b2   = (const float*)d_in[28];
  float* outp = (float*)d_out;

  char* ws = (char*)d_ws;
  size_t off = 0;
  auto alloc = [&](size_t bytes) -> void* {
    void* p = ws + off;
    off = (off + bytes + 255) & ~(size_t)255;
    return p;
  };
  float*  h0     = (float*)alloc((size_t)NN * HIDD * 4);
  float*  h1     = (float*)alloc((size_t)NN * HIDD * 4);
  float*  qf     = (float*)alloc((size_t)NN * HIDD * 4);
  float*  sf     = (float*)alloc((size_t)NN * HIDD * 4);
  unsigned short* kvb = (unsigned short*)alloc((size_t)NN * 256 * 2);
  short*  wT     = (short*)alloc((size_t)163840 * 2);
  int*    starts = (int*)alloc((size_t)(NN + 1) * 4);
  int*    pos    = (int*)alloc((size_t)NN * 4);
  int*    csr    = (int*)alloc((size_t)EE * 4);
  int*    btot   = (int*)alloc((size_t)NB1 * 4);
  int*    boff   = (int*)alloc((size_t)NB1 * 4);
  float*  g      = (float*)alloc((size_t)NG * HIDD * 4);
  float*  gcnt   = (float*)alloc((size_t)NG * 4);
  (void)ws_size; (void)in_sizes; (void)n_in; (void)out_size;

  // ---- weight prep (transpose + bf16 cast) ----
  PrepW pw = {{l0_Wq, l0_Wk, l0_Wv, l0_Ws,
               Wq, Wk, Wv, Ws,
               Wq + 16384, Wk + 16384, Wv + 16384, Ws + 16384}};
  prep_kernel<<<640, 256, 0, stream>>>(pw, wT);

  // ---- CSR build (by dst) ----
  hipMemsetAsync(pos, 0, (size_t)NN * 4, stream);
  count_kernel<<<(EE + 255) / 256, 256, 0, stream>>>(ei, pos, EE);
  scan1_kernel<<<NB1, 1024, 0, stream>>>(pos, starts, btot);
  scan2_kernel<<<1, 64, 0, stream>>>(btot, boff, starts);
  scan3_kernel<<<(NN + 255) / 256, 256, 0, stream>>>(starts, boff, pos);
  scatter_kernel<<<(EE + 255) / 256, 256, 0, stream>>>(ei, pos, csr, EE);

  int ggrid = (NN + 31) / 32;
  int agrid = (NN + 3) / 4;
  const unsigned* kvu = (const unsigned*)kvb;

  // ---- layer 0 (64 -> 128) ----
  BiasW b0 = {{l0_bq, l0_bk, l0_bv, l0_bs}};
  gemm_qkvs<DIN><<<ggrid, 256, 0, stream>>>(x, wT, b0, qf, kvb, sf, NN);
  attn_fused<<<agrid, 256, 0, stream>>>(qf, kvu, sf, starts, csr, l0_Wbeta,
                                        l0_lng, l0_lnb, h0, NN);

  // ---- layer 1 ----
  BiasW b1s = {{bq, bk, bv, bs}};
  gemm_qkvs<HIDD><<<ggrid, 256, 0, stream>>>(h0, wT + 32768, b1s, qf, kvb, sf, NN);
  attn_fused<<<agrid, 256, 0, stream>>>(qf, kvu, sf, starts, csr, Wbeta,
                                        lng, lnb, h1, NN);

  // ---- layer 2 ----
  BiasW b2s = {{bq + HIDD, bk + HIDD, bv + HIDD, bs + HIDD}};
  gemm_qkvs<HIDD><<<ggrid, 256, 0, stream>>>(h1, wT + 98304, b2s, qf, kvb, sf, NN);
  attn_fused<<<agrid, 256, 0, stream>>>(qf, kvu, sf, starts, csr, Wbeta + 384,
                                        lng + HIDD, lnb + HIDD, h0, NN);

  // ---- pool + MLP ----
  hipMemsetAsync(g, 0, (size_t)NG * HIDD * 4, stream);
  hipMemsetAsync(gcnt, 0, (size_t)NG * 4, stream);
  pool_kernel<<<256, 256, 0, stream>>>(h0, batch, g, gcnt, NN);
  final_kernel<<<1, 256, 0, stream>>>(g, gcnt, mlp_W1, mlp_b1, mlp_W2, mlp_b2, outp);
}

// Round 5
// 569.661 us; speedup vs baseline: 1.0060x; 1.0060x over previous
//
#include <hip/hip_runtime.h>
#include <hip/hip_bf16.h>

#define NN 50000
#define EE 500000
#define DIN 64
#define HIDD 128
#define NG 64
#define NB1 49  // ceil(NN/1024) scan blocks

typedef short short8 __attribute__((ext_vector_type(8)));
typedef float f32x4 __attribute__((ext_vector_type(4)));

__device__ __forceinline__ short f2bf(float f) {
  unsigned u = __float_as_uint(f);
  u += 0x7fffu + ((u >> 16) & 1u);  // RNE
  return (short)(u >> 16);
}

struct BiasW { const float* b[4]; };
struct PrepW { const float* w[12]; };

// ---------------- CSR build ----------------
__global__ __launch_bounds__(256) void count_kernel(const int* __restrict__ ei,
                                                    int* __restrict__ cnt, int E) {
  int e = blockIdx.x * 256 + threadIdx.x;
  if (e < E) atomicAdd(&cnt[ei[E + e]], 1);
}

__global__ __launch_bounds__(1024) void scan1_kernel(const int* __restrict__ cnts,
                                                     int* __restrict__ starts,
                                                     int* __restrict__ btot) {
  __shared__ int sh[1024];
  int t = threadIdx.x;
  int idx = blockIdx.x * 1024 + t;
  int v = (idx < NN) ? cnts[idx] : 0;
  sh[t] = v;
  __syncthreads();
  for (int off = 1; off < 1024; off <<= 1) {
    int add = (t >= off) ? sh[t - off] : 0;
    __syncthreads();
    sh[t] += add;
    __syncthreads();
  }
  if (idx < NN) starts[idx] = sh[t] - v;
  if (t == 1023) btot[blockIdx.x] = sh[1023];
}

__global__ __launch_bounds__(64) void scan2_kernel(const int* __restrict__ btot,
                                                   int* __restrict__ boff,
                                                   int* __restrict__ starts) {
  int t = threadIdx.x;
  int orig = (t < NB1) ? btot[t] : 0;
  int v = orig;
  for (int off = 1; off < 64; off <<= 1) {
    int n_ = __shfl_up(v, off);
    if (t >= off) v += n_;
  }
  if (t < NB1) boff[t] = v - orig;
  if (t == NB1 - 1) starts[NN] = v;
}

__global__ __launch_bounds__(256) void scan3_kernel(int* __restrict__ starts,
                                                    const int* __restrict__ boff,
                                                    int* __restrict__ pos) {
  int i = blockIdx.x * 256 + threadIdx.x;
  if (i < NN) {
    int s = starts[i] + boff[i >> 10];
    starts[i] = s;
    pos[i] = s;
  }
}

__global__ __launch_bounds__(256) void scatter_kernel(const int* __restrict__ ei,
                                                      int* __restrict__ pos,
                                                      int* __restrict__ csr_src, int E) {
  int e = blockIdx.x * 256 + threadIdx.x;
  if (e < E) {
    int dst = ei[E + e];
    int p = atomicAdd(&pos[dst], 1);
    csr_src[p] = ei[e];
  }
}

// ---------------- weight prep: transpose + cast to bf16 ----------------
// wT layout: mats 0..3 (l0, K=64): [128][64] at m*8192
//            mats 4..11 (layers, K=128): [128][128] at 32768+(m-4)*16384
__global__ __launch_bounds__(256) void prep_kernel(PrepW pw, short* __restrict__ wT) {
  int o = blockIdx.x * 256 + threadIdx.x;
  if (o >= 163840) return;
  int m, local, K;
  if (o < 32768) { m = o >> 13; local = o & 8191; K = 64; }
  else { int oo = o - 32768; m = 4 + (oo >> 14); local = oo & 16383; K = 128; }
  int n = (K == 64) ? (local >> 6) : (local >> 7);
  int k = local & (K - 1);
  wT[o] = f2bf(pw.w[m][(size_t)k * 128 + n]);
}

// ---------------- bf16 MFMA GEMM: h[N,K] x W[K,128], 4 mats fused ----------------
// 512 threads = 8 waves = 4 row-groups x 2 col-halves; 64 rows/block; grid ceil(N/64).
// B read directly from L2-resident wT (no LDS round-trip — R4's swizzle aliased).
// mat 0 -> Q (f32), 1 -> K (bf16 kv[:,0:128]), 2 -> V (bf16 kv[:,128:256]), 3 -> S (f32)
template <int K>
__global__ __launch_bounds__(512, 4) void gemm_qkvs(
    const float* __restrict__ h, const short* __restrict__ wT, BiasW bw,
    float* __restrict__ qf, unsigned short* __restrict__ kvb,
    float* __restrict__ sf, int N) {
  __shared__ short aS[64 * K];
  constexpr int SLOTS = K / 8;
  constexpr int RB = 2 * K;
  const int n0 = blockIdx.x * 64;
  const int t = threadIdx.x;

  // stage A tile (64 x K): f32 -> bf16, XOR-swizzled rows
  for (int idx = t; idx < 64 * SLOTS; idx += 512) {
    int row = idx / SLOTS, slot = idx % SLOTS;
    int gr = n0 + row;
    float4 f0 = make_float4(0.f, 0.f, 0.f, 0.f), f1 = f0;
    if (gr < N) {
      const float* hp = &h[(size_t)gr * K + slot * 8];
      f0 = *(const float4*)hp;
      f1 = *(const float4*)(hp + 4);
    }
    short8 pk;
    pk[0] = f2bf(f0.x); pk[1] = f2bf(f0.y); pk[2] = f2bf(f0.z); pk[3] = f2bf(f0.w);
    pk[4] = f2bf(f1.x); pk[5] = f2bf(f1.y); pk[6] = f2bf(f1.z); pk[7] = f2bf(f1.w);
    unsigned byte = row * RB + ((slot * 16) ^ ((row & 7) << 4));
    *(short8*)((char*)aS + byte) = pk;
  }
  __syncthreads();

  const int l = t & 63, wv = t >> 6;       // 8 waves
  const int lr = l & 15, lk = l >> 4;
  const int rowg = wv >> 1;                // 4 row-groups of 16
  const int colbase = (wv & 1) * 64;       // 2 col-halves
  const int arow = rowg * 16 + lr;

  short8 afrag[K / 32];
#pragma unroll
  for (int ks = 0; ks < K / 32; ++ks) {
    unsigned ab = arow * RB + ((((ks * 4 + lk) * 16)) ^ ((arow & 7) << 4));
    afrag[ks] = *(const short8*)((const char*)aS + ab);
  }

#pragma unroll
  for (int mat = 0; mat < 4; ++mat) {
    const short* __restrict__ w = wT + (size_t)mat * 128 * K;
    f32x4 acc[4] = {};
#pragma unroll
    for (int ks = 0; ks < K / 32; ++ks) {
#pragma unroll
      for (int cf = 0; cf < 4; ++cf) {
        int col = colbase + cf * 16 + lr;
        short8 b = *(const short8*)&w[(size_t)col * K + ks * 32 + lk * 8];
        acc[cf] = __builtin_amdgcn_mfma_f32_16x16x32_bf16(afrag[ks], b, acc[cf], 0, 0, 0);
      }
    }
    const float* __restrict__ bias = bw.b[mat];
#pragma unroll
    for (int cf = 0; cf < 4; ++cf) {
      int col = colbase + cf * 16 + lr;
      float bv = bias[col];
#pragma unroll
      for (int r = 0; r < 4; ++r) {
        int row = n0 + rowg * 16 + lk * 4 + r;
        if (row < N) {
          float val = acc[cf][r] + bv;
          if (mat == 0) qf[(size_t)row * 128 + col] = val;
          else if (mat == 3) sf[(size_t)row * 128 + col] = val;
          else kvb[(size_t)row * 256 + (mat == 2 ? 128 : 0) + col] = (unsigned short)f2bf(val);
        }
      }
    }
  }
}

// ---------------- fused attention + beta gate + LN + GELU ----------------
// one wave per node. lanes 0-31 own K-side (4 channels each), lanes 32-63 own
// V-side/output. ONE uint2 (8B) gather per edge per lane (512B row coverage).
__global__ __launch_bounds__(256, 8) void attn_fused(
    const float* __restrict__ qf, const unsigned* __restrict__ kvu,
    const float* __restrict__ sf, const int* __restrict__ starts,
    const int* __restrict__ csr, const float* __restrict__ Wbeta,
    const float* __restrict__ lng, const float* __restrict__ lnb,
    float* __restrict__ hout, int N) {
  int wid = (blockIdx.x * 256 + threadIdx.x) >> 6;
  if (wid >= N) return;
  const int lane = threadIdx.x & 63;
  const int cl = lane & 31;  // channel group: channels 4*cl .. 4*cl+3
  const float scale = 0.17677669529663687f;  // 1/sqrt(32)
  float4 q4 = *(const float4*)&qf[(size_t)wid * 128 + 4 * cl];
  q4.x *= scale; q4.y *= scale; q4.z *= scale; q4.w *= scale;
  int s0 = starts[wid], s1 = starts[wid + 1];
  float d = 0.f, ox = 0.f, oy = 0.f, oz = 0.f, ow = 0.f;
  for (int i = s0; i < s1; i += 8) {
    int src[8];
#pragma unroll
    for (int e = 0; e < 8; ++e) {
      int idx = i + e;
      idx = (idx < s1) ? idx : (s1 - 1);
      src[e] = csr[idx];
    }
    uint2 wv2[8];
#pragma unroll
    for (int e = 0; e < 8; ++e)
      wv2[e] = *(const uint2*)&kvu[(size_t)src[e] * 128 + 2 * lane];
#pragma unroll
    for (int e = 0; e < 8; ++e) {
      float fx = __uint_as_float(wv2[e].x << 16);
      float fy = __uint_as_float(wv2[e].x & 0xffff0000u);
      float fz = __uint_as_float(wv2[e].y << 16);
      float fw = __uint_as_float(wv2[e].y & 0xffff0000u);
      float part = q4.x * fx + q4.y * fy + q4.z * fz + q4.w * fw;
      part += __shfl_xor(part, 1);
      part += __shfl_xor(part, 2);
      part += __shfl_xor(part, 4);  // head-sum over 8 lanes
      float p = __expf(part);
      p = (i + e < s1) ? p : 0.f;
      float pm = __shfl(p, cl);  // broadcast head-p to matching V lane
      d += p;                    // meaningful in lanes 0-31
      ox = fmaf(pm, fx, ox); oy = fmaf(pm, fy, oy);  // meaningful in lanes 32-63
      oz = fmaf(pm, fz, oz); ow = fmaf(pm, fw, ow);
    }
  }
  float dv = __shfl(d, cl);
  float inv = dv > 0.f ? 1.f / dv : 0.f;
  ox *= inv; oy *= inv; oz *= inv; ow *= inv;
  float4 sv4 = *(const float4*)&sf[(size_t)wid * 128 + 4 * cl];
  float4 wbo = *(const float4*)&Wbeta[4 * cl];
  float4 wbx = *(const float4*)&Wbeta[128 + 4 * cl];
  float4 wbd = *(const float4*)&Wbeta[256 + 4 * cl];
  float bl = ox * wbo.x + oy * wbo.y + oz * wbo.z + ow * wbo.w
           + sv4.x * wbx.x + sv4.y * wbx.y + sv4.z * wbx.z + sv4.w * wbx.w
           + (ox - sv4.x) * wbd.x + (oy - sv4.y) * wbd.y
           + (oz - sv4.z) * wbd.z + (ow - sv4.w) * wbd.w;
  bl += __shfl_xor(bl, 1);  bl += __shfl_xor(bl, 2);  bl += __shfl_xor(bl, 4);
  bl += __shfl_xor(bl, 8);  bl += __shfl_xor(bl, 16);  // sum over 32-lane half
  float beta = 1.f / (1.f + __expf(-bl));
  float hx = beta * sv4.x + (1.f - beta) * ox;
  float hy = beta * sv4.y + (1.f - beta) * oy;
  float hz = beta * sv4.z + (1.f - beta) * oz;
  float hw = beta * sv4.w + (1.f - beta) * ow;
  float s = hx + hy + hz + hw;
  float sq = hx * hx + hy * hy + hz * hz + hw * hw;
  s += __shfl_xor(s, 1);  sq += __shfl_xor(sq, 1);
  s += __shfl_xor(s, 2);  sq += __shfl_xor(sq, 2);
  s += __shfl_xor(s, 4);  sq += __shfl_xor(sq, 4);
  s += __shfl_xor(s, 8);  sq += __shfl_xor(sq, 8);
  s += __shfl_xor(s, 16); sq += __shfl_xor(sq, 16);
  float mu = s * (1.f / 128.f);
  float var = sq * (1.f / 128.f) - mu * mu;
  float rstd = 1.f / sqrtf(var + 1e-5f);
  float4 g4 = *(const float4*)&lng[4 * cl];
  float4 b4 = *(const float4*)&lnb[4 * cl];
  float y0 = (hx - mu) * rstd * g4.x + b4.x;
  float y1 = (hy - mu) * rstd * g4.y + b4.y;
  float y2 = (hz - mu) * rstd * g4.z + b4.z;
  float y3 = (hw - mu) * rstd * g4.w + b4.w;
  y0 = 0.5f * y0 * (1.f + erff(y0 * 0.70710678118654752f));
  y1 = 0.5f * y1 * (1.f + erff(y1 * 0.70710678118654752f));
  y2 = 0.5f * y2 * (1.f + erff(y2 * 0.70710678118654752f));
  y3 = 0.5f * y3 * (1.f + erff(y3 * 0.70710678118654752f));
  if (lane >= 32) {
    float4 o = make_float4(y0, y1, y2, y3);
    *(float4*)&hout[(size_t)wid * 128 + 4 * cl] = o;
  }
}

// ---------------- mean pool ----------------
__global__ __launch_bounds__(256) void pool_kernel(const float* __restrict__ h,
    const int* __restrict__ batch, float* __restrict__ g,
    float* __restrict__ gcnt, int N) {
  __shared__ float accS[NG * HIDD];
  __shared__ float cntS[NG];
  int t = threadIdx.x;
  for (int i = t; i < NG * HIDD; i += 256) accS[i] = 0.f;
  if (t < NG) cntS[t] = 0.f;
  __syncthreads();
  int lane = t & 63, grp = t >> 6;
  for (int n = blockIdx.x * 4 + grp; n < N; n += gridDim.x * 4) {
    int b = batch[n];
    float2 hv = *(const float2*)&h[(size_t)n * HIDD + (lane << 1)];
    atomicAdd(&accS[b * HIDD + (lane << 1)], hv.x);
    atomicAdd(&accS[b * HIDD + (lane << 1) + 1], hv.y);
    if (lane == 0) atomicAdd(&cntS[b], 1.f);
  }
  __syncthreads();
  for (int i = t; i < NG * HIDD; i += 256)
    if (accS[i] != 0.f) atomicAdd(&g[i], accS[i]);
  if (t < NG && cntS[t] != 0.f) atomicAdd(&gcnt[t], cntS[t]);
}

// ---------------- final MLP (single block) ----------------
__global__ __launch_bounds__(256) void final_kernel(const float* __restrict__ g,
    const float* __restrict__ gcnt, const float* __restrict__ W1,
    const float* __restrict__ b1, const float* __restrict__ W2,
    const float* __restrict__ b2, float* __restrict__ out) {
  __shared__ float gS[NG * HIDD];
  __shared__ float hmS[NG * HIDD];
  int t = threadIdx.x;
  for (int i = t; i < NG * HIDD; i += 256) {
    int gr = i >> 7;
    gS[i] = g[i] / fmaxf(gcnt[gr], 1.f);
  }
  __syncthreads();
  for (int i = t; i < NG * HIDD; i += 256) {
    int gr = i >> 7, col = i & 127;
    float s = b1[col];
    for (int k = 0; k < HIDD; ++k) s = fmaf(gS[gr * HIDD + k], W1[k * HIDD + col], s);
    hmS[i] = 0.5f * s * (1.f + erff(s * 0.70710678118654752f));
  }
  __syncthreads();
  if (t < NG) {
    float s = b2[0];
    for (int k = 0; k < HIDD; ++k) s = fmaf(hmS[t * HIDD + k], W2[k], s);
    out[t] = s;
  }
}

extern "C" void kernel_launch(void* const* d_in, const int* in_sizes, int n_in,
                              void* d_out, int out_size, void* d_ws, size_t ws_size,
                              hipStream_t stream) {
  const float* x        = (const float*)d_in[0];
  const int*   ei       = (const int*)d_in[1];
  const int*   batch    = (const int*)d_in[2];
  const float* l0_Wq    = (const float*)d_in[3];
  const float* l0_bq    = (const float*)d_in[4];
  const float* l0_Wk    = (const float*)d_in[5];
  const float* l0_bk    = (const float*)d_in[6];
  const float* l0_Wv    = (const float*)d_in[7];
  const float* l0_bv    = (const float*)d_in[8];
  const float* l0_Ws    = (const float*)d_in[9];
  const float* l0_bs    = (const float*)d_in[10];
  const float* l0_Wbeta = (const float*)d_in[11];
  const float* l0_lng   = (const float*)d_in[12];
  const float* l0_lnb   = (const float*)d_in[13];
  const float* Wq       = (const float*)d_in[14];
  const float* bq       = (const float*)d_in[15];
  const float* Wk       = (const float*)d_in[16];
  const float* bk       = (const float*)d_in[17];
  const float* Wv       = (const float*)d_in[18];
  const float* bv       = (const float*)d_in[19];
  const float* Ws       = (const float*)d_in[20];
  const float* bs       = (const float*)d_in[21];
  const float* Wbeta    = (const float*)d_in[22];
  const float* lng      = (const float*)d_in[23];
  const float* lnb      = (const float*)d_in[24];
  const float* mlp_W1   = (const float*)d_in[25];
  const float* mlp_b1   = (const float*)d_in[26];
  const float* mlp_W2   = (const float*)d_in[27];
  const float* mlp_b2   = (const float*)d_in[28];
  float* outp = (float*)d_out;

  char* ws = (char*)d_ws;
  size_t off = 0;
  auto alloc = [&](size_t bytes) -> void* {
    void* p = ws + off;
    off = (off + bytes + 255) & ~(size_t)255;
    return p;
  };
  float*  h0     = (float*)alloc((size_t)NN * HIDD * 4);
  float*  h1     = (float*)alloc((size_t)NN * HIDD * 4);
  float*  qf     = (float*)alloc((size_t)NN * HIDD * 4);
  float*  sf     = (float*)alloc((size_t)NN * HIDD * 4);
  unsigned short* kvb = (unsigned short*)alloc((size_t)NN * 256 * 2);
  short*  wT     = (short*)alloc((size_t)163840 * 2);
  int*    starts = (int*)alloc((size_t)(NN + 1) * 4);
  int*    pos    = (int*)alloc((size_t)NN * 4);
  int*    csr    = (int*)alloc((size_t)EE * 4);
  int*    btot   = (int*)alloc((size_t)NB1 * 4);
  int*    boff   = (int*)alloc((size_t)NB1 * 4);
  float*  g      = (float*)alloc((size_t)NG * HIDD * 4);
  float*  gcnt   = (float*)alloc((size_t)NG * 4);
  (void)ws_size; (void)in_sizes; (void)n_in; (void)out_size;

  // ---- weight prep (transpose + bf16 cast) ----
  PrepW pw = {{l0_Wq, l0_Wk, l0_Wv, l0_Ws,
               Wq, Wk, Wv, Ws,
               Wq + 16384, Wk + 16384, Wv + 16384, Ws + 16384}};
  prep_kernel<<<640, 256, 0, stream>>>(pw, wT);

  // ---- CSR build (by dst) ----
  hipMemsetAsync(pos, 0, (size_t)NN * 4, stream);
  count_kernel<<<(EE + 255) / 256, 256, 0, stream>>>(ei, pos, EE);
  scan1_kernel<<<NB1, 1024, 0, stream>>>(pos, starts, btot);
  scan2_kernel<<<1, 64, 0, stream>>>(btot, boff, starts);
  scan3_kernel<<<(NN + 255) / 256, 256, 0, stream>>>(starts, boff, pos);
  scatter_kernel<<<(EE + 255) / 256, 256, 0, stream>>>(ei, pos, csr, EE);

  int ggrid = (NN + 63) / 64;
  int agrid = (NN + 3) / 4;
  const unsigned* kvu = (const unsigned*)kvb;

  // ---- layer 0 (64 -> 128) ----
  BiasW b0 = {{l0_bq, l0_bk, l0_bv, l0_bs}};
  gemm_qkvs<DIN><<<ggrid, 512, 0, stream>>>(x, wT, b0, qf, kvb, sf, NN);
  attn_fused<<<agrid, 256, 0, stream>>>(qf, kvu, sf, starts, csr, l0_Wbeta,
                                        l0_lng, l0_lnb, h0, NN);

  // ---- layer 1 ----
  BiasW b1s = {{bq, bk, bv, bs}};
  gemm_qkvs<HIDD><<<ggrid, 512, 0, stream>>>(h0, wT + 32768, b1s, qf, kvb, sf, NN);
  attn_fused<<<agrid, 256, 0, stream>>>(qf, kvu, sf, starts, csr, Wbeta,
                                        lng, lnb, h1, NN);

  // ---- layer 2 ----
  BiasW b2s = {{bq + HIDD, bk + HIDD, bv + HIDD, bs + HIDD}};
  gemm_qkvs<HIDD><<<ggrid, 512, 0, stream>>>(h1, wT + 98304, b2s, qf, kvb, sf, NN);
  attn_fused<<<agrid, 256, 0, stream>>>(qf, kvu, sf, starts, csr, Wbeta + 384,
                                        lng + HIDD, lnb + HIDD, h0, NN);

  // ---- pool + MLP ----
  hipMemsetAsync(g, 0, (size_t)NG * HIDD * 4, stream);
  hipMemsetAsync(gcnt, 0, (size_t)NG * 4, stream);
  pool_kernel<<<256, 256, 0, stream>>>(h0, batch, g, gcnt, NN);
  final_kernel<<<1, 256, 0, stream>>>(g, gcnt, mlp_W1, mlp_b1, mlp_W2, mlp_b2, outp);
}